// Round 7
// baseline (3126.101 us; speedup 1.0000x reference)
//
#include <hip/hip_runtime.h>
#include <hip/hip_fp16.h>

typedef _Float16 h2v __attribute__((ext_vector_type(2)));
typedef _Float16 f16x8 __attribute__((ext_vector_type(8)));
typedef float f32x4 __attribute__((ext_vector_type(4)));
typedef unsigned int u32;
typedef unsigned short u16;

#define NP 512
#define NH 256
#define NT 1024
#define NBLK 16     // 16 blocks x 16 batch rows
#define ROWS 16

// ws layout in dwords
// WH: B-frags for h@Wh. dword F = (((w*24 + f)*64 + l)*4 + d), f = g*8 + kt
//   (g = gate 0..2, kt = K-tile 0..7, w = wave 0..15)
//   k = kt*32 + (l>>4)*8 + 2d (+1 hi), col = g*256 + w*16 + (l&15)
#define OFF_WH 0
#define LEN_WH 98304            // 16 * 24 * 64 * 4
// WIB: Wi B-frags (K=32 single tile, rows >=17 zero) — layout HW-verified r6
//   dword F-OFF = ((w*3 + g)*64 + l)*4 + d ; k = (l>>4)*8 + 2d
//   col = g*256 + w*16 + (l&15)
#define OFF_WIB (OFF_WH + LEN_WH)      // 98304
#define LEN_WIB 12288           // 16 * 3 * 64 * 4
#define OFF_W1 (OFF_WIB + LEN_WIB)     // 110592
#define LEN_W1 68096            // 2 * 133 * 256
#define OFF_W2 (OFF_W1 + LEN_W1)       // 178688
#define LEN_W2 65536            // 2 * 128 * 256
#define OFF_W3 (OFF_W2 + LEN_W2)       // 244224
#define LEN_W3 256              // 2 * 128
#define WS_DWORDS (OFF_W3 + LEN_W3)    // 244480 dwords

__device__ __forceinline__ u32 pack2(float lo, float hi) {
    h2v v; v.x = (_Float16)lo; v.y = (_Float16)hi;
    return __builtin_bit_cast(u32, v);
}

__device__ __forceinline__ float fdot2(u32 a, u32 b, float c) {
#if __has_builtin(__builtin_amdgcn_fdot2)
    return __builtin_amdgcn_fdot2(__builtin_bit_cast(h2v, a),
                                  __builtin_bit_cast(h2v, b), c, false);
#else
    h2v x = __builtin_bit_cast(h2v, a), y = __builtin_bit_cast(h2v, b);
    return c + (float)x.x * (float)y.x + (float)x.y * (float)y.y;
#endif
}

// ---------------- pack kernel ----------------
__global__ __launch_bounds__(256) void pack_kernel(
    const float* __restrict__ Wi, const float* __restrict__ Whrz,
    const float* __restrict__ Whn, const float* __restrict__ W1,
    const float* __restrict__ W2, const float* __restrict__ W3,
    u32* __restrict__ ws)
{
    for (int F = blockIdx.x * 256 + threadIdx.x; F < WS_DWORDS; F += gridDim.x * 256) {
        u32 val;
        if (F < OFF_WIB) {
            int d = F & 3; int r = F >> 2;
            int l = r & 63; int q = r >> 6;      // q = w*24 + f
            int f = q % 24; int w = q / 24;      // w 0..15
            int g = f >> 3; int kt = f & 7;
            int k = kt * 32 + ((l >> 4) << 3) + 2 * d;
            int col = g * 256 + w * 16 + (l & 15);
            float lo, hi;
            if (col < 512) { lo = Whrz[k * 512 + col]; hi = Whrz[(k + 1) * 512 + col]; }
            else { lo = Whn[k * 256 + (col - 512)]; hi = Whn[(k + 1) * 256 + (col - 512)]; }
            val = pack2(lo, hi);
        } else if (F < OFF_W1) {
            int j = F - OFF_WIB;
            int d = j & 3; int r = j >> 2;
            int l = r & 63; int q2 = r >> 6;     // q2 = w*3 + g
            int g = q2 % 3; int w = q2 / 3;
            int k = ((l >> 4) << 3) + 2 * d;
            int col = g * 256 + w * 16 + (l & 15);
            float lo = (k < 17) ? Wi[k * 768 + col] : 0.f;
            float hi = (k + 1 < 17) ? Wi[(k + 1) * 768 + col] : 0.f;
            val = pack2(lo, hi);
        } else if (F < OFF_W2) {
            int j = F - OFF_W1; int c = j / (133 * 256); int r = j % (133 * 256);
            int kk = r >> 8; int o = r & 255;
            int k = 2 * kk;
            float lo = W1[(c * 265 + k) * 256 + o];
            float hi = (k + 1 < 265) ? W1[(c * 265 + k + 1) * 256 + o] : 0.f;
            val = pack2(lo, hi);
        } else if (F < OFF_W3) {
            int j = F - OFF_W2; int c = j >> 15; int r = j & 32767;
            int kk = r >> 8; int o = r & 255;
            float lo = W2[(c * 256 + 2 * kk) * 256 + o];
            float hi = W2[(c * 256 + 2 * kk + 1) * 256 + o];
            val = pack2(lo, hi);
        } else {
            int j = F - OFF_W3; int c = j >> 7; int jj = j & 127;
            float lo = W3[c * 256 + 2 * jj];
            float hi = W3[c * 256 + 2 * jj + 1];
            val = pack2(lo, hi);
        }
        ws[F] = val;
    }
}

// ---------------- main kernel: 16 batch rows per workgroup --------------
// A-frag rows = 16 batch rows (row = lane&15, HW-verified via r6's x@Wi).
// Wave w owns cols [w*16, w*16+16) of each gate; per step it computes
// 3 x@Wi tiles (C-init for r/z; n kept separate) + 24 chained h@Wh tiles.
// C layout gives each lane r/z/n for (row = (lane>>4)*4+reg, col), so the
// GRU update is fully in-lane; h carried in 4 regs/lane; h also written
// fp16 to a double-buffered XOR-swizzled LDS tile for next step's A-frags.
// One barrier per step. x staged per 16-step chunk with register prefetch.
__global__ __launch_bounds__(1024, 4) void qnet_kernel(
    const float* __restrict__ particles, const float* __restrict__ pweights,
    const float* __restrict__ actions, const float* __restrict__ timev,
    const float* __restrict__ bi, const float* __restrict__ bn,
    const float* __restrict__ b1, const float* __restrict__ b2,
    const float* __restrict__ b3, const int* __restrict__ nts,
    const u32* __restrict__ ws, float* __restrict__ out)
{
    __shared__ __align__(16) u32 smem[15360];       // 61.4 KB, overlaid
    __shared__ __align__(16) float sMisc[ROWS][12]; // actions + norm_time

    // scan-phase views
    u32* sXc = smem;                       // [256 slots][20 dw] x chunk (fp16 pairs)
    u16* sH0 = (u16*)(smem + 5120);        // [16][256] h fp16, swizzled
    u16* sH1 = (u16*)(smem + 7168);
    // tail views (scan arrays dead by then)
    float* sHf = (float*)smem;             // [16][256] f32
    u32* sHid = smem + 4096;               // [16][136]
    u32* sL1  = smem + 6272;               // [16][2][128] (u16 pairs)
    u32* sL2  = smem + 10368;              // [16][2][128]

    const int bg = blockIdx.x;
    const int tid = threadIdx.x;
    const int lane = tid & 63;
    const int wid = tid >> 6;      // 0..15
    const int l15 = lane & 15;
    const int kq  = lane >> 4;     // 0..3

    // ---- B-frags (108 dwords/lane -> AGPR under the 128-V cap) ----
    f16x8 bh[24];
    {
        const uint4* gp = (const uint4*)(ws + OFF_WH) + (wid * 24) * 64 + lane;
        #pragma unroll
        for (int i = 0; i < 24; ++i) bh[i] = __builtin_bit_cast(f16x8, gp[i * 64]);
    }
    f16x8 wibR, wibZ, wibN;
    {
        const uint4* wp = (const uint4*)(ws + OFF_WIB) + (wid * 3) * 64 + lane;
        wibR = __builtin_bit_cast(f16x8, wp[0]);
        wibZ = __builtin_bit_cast(f16x8, wp[64]);
        wibN = __builtin_bit_cast(f16x8, wp[128]);
    }

    // ---- init: zero h buf0; zero sXc pad dwords (9..15, never rewritten) ----
    for (int j = tid; j < ROWS * NH; j += NT) sH0[j] = 0;
    for (int j = tid; j < 256 * 7; j += NT) {
        int slot = j / 7, d = 9 + j % 7;
        sXc[slot * 20 + d] = 0u;
    }
    if (tid < ROWS * 9) {
        int row = tid / 9, i = tid % 9;
        sMisc[row][i] = (i < 8) ? actions[(bg * ROWS + row) * 8 + i]
                                : timev[bg * ROWS + row] / (float)nts[0];
    }

    // ---- per-lane gate biases (col j = wid*16 + l15) ----
    const int jcol = wid * 16 + l15;
    const float birL = bi[jcol], bizL = bi[NH + jcol];
    const float binL = bi[2 * NH + jcol], bnnL = bn[jcol];
    float hprev[4] = {0.f, 0.f, 0.f, 0.f};

    // ---- chunk-staging thread roles + prefetch chunk 0 ----
    const int srow = tid >> 6;         // 0..15
    const int sst  = (tid >> 2) & 15;  // step within chunk
    const int sq4  = tid & 3;          // float4 quarter
    const float4* pfp = (const float4*)(particles
        + ((long)(bg * ROWS + srow) * NP + sst) * 16 + sq4 * 4);
    const float* pwp = pweights + (long)(bg * ROWS + srow) * NP + sst;
    float4 pf = pfp[0];
    float pfw = (sq4 == 0) ? pwp[0] : 0.f;

    __syncthreads();

    u16* hcur = sH0;
    u16* hnxt = sH1;
    const int rb  = l15 * 512;          // row base (bytes)
    const int swz = (l15 & 7) << 4;     // row XOR swizzle
    const int kqb = kq * 16;

    #pragma unroll 1
    for (int p = 0; p < NP; ++p) {
        if ((p & 15) == 0) {
            // commit prefetched chunk to LDS
            u32* dst = &sXc[(sst * 16 + srow) * 20 + sq4 * 2];
            dst[0] = pack2(pf.x, pf.y);
            dst[1] = pack2(pf.z, pf.w);
            if (sq4 == 0) sXc[(sst * 16 + srow) * 20 + 8] = pack2(pfw, 0.f);
            __syncthreads();
            if (p + 16 < NP) {                  // prefetch next chunk
                pf = pfp[(p + 16) * 4];
                if (sq4 == 0) pfw = pwp[p + 16];
            }
        }
        // ---- x@Wi A-frag (rows = batch rows, K=32) ----
        f16x8 ax = __builtin_bit_cast(f16x8,
            *(const uint4*)&sXc[((p & 15) * 16 + l15) * 20 + kq * 4]);
        f32x4 z4 = {0.f, 0.f, 0.f, 0.f};
        f32x4 aR  = __builtin_amdgcn_mfma_f32_16x16x32_f16(ax, wibR, z4, 0, 0, 0);
        f32x4 aZ  = __builtin_amdgcn_mfma_f32_16x16x32_f16(ax, wibZ, z4, 0, 0, 0);
        f32x4 aNx = __builtin_amdgcn_mfma_f32_16x16x32_f16(ax, wibN, z4, 0, 0, 0);
        f32x4 aNh = z4;
        // ---- h@Wh: 8 chained K-tiles, A from swizzled LDS ----
        const char* hb = (const char*)hcur;
        #pragma unroll
        for (int kt = 0; kt < 8; ++kt) {
            int off = rb + (((kt << 6) + kqb) ^ swz);
            f16x8 ah = __builtin_bit_cast(f16x8, *(const uint4*)(hb + off));
            aR  = __builtin_amdgcn_mfma_f32_16x16x32_f16(ah, bh[kt],      aR,  0, 0, 0);
            aZ  = __builtin_amdgcn_mfma_f32_16x16x32_f16(ah, bh[8 + kt],  aZ,  0, 0, 0);
            aNh = __builtin_amdgcn_mfma_f32_16x16x32_f16(ah, bh[16 + kt], aNh, 0, 0, 0);
        }
        // ---- gates in-lane: (row = kq*4 + r, col = jcol) ----
        #pragma unroll
        for (int r = 0; r < 4; ++r) {
            int row = kq * 4 + r;
            float rg = 1.f / (1.f + __expf(-(aR[r] + birL)));
            float zg = 1.f / (1.f + __expf(-(aZ[r] + bizL)));
            float targ = aNx[r] + binL + rg * (aNh[r] + bnnL);
            float e2 = __expf(2.f * targ);
            float n = 1.f - 2.f / (e2 + 1.f);
            hprev[r] = (1.f - zg) * n + zg * hprev[r];
            _Float16 hh = (_Float16)hprev[r];
            int wb = row * 512 + ((jcol * 2) ^ ((row & 7) << 4));
            *(u16*)((char*)hnxt + wb) = __builtin_bit_cast(u16, hh);
        }
        __syncthreads();
        u16* t = hcur; hcur = hnxt; hnxt = t;
    }

    // ---------------- MLP tail (16 rows) ----------------
    #pragma unroll
    for (int r = 0; r < 4; ++r) sHf[(kq * 4 + r) * NH + jcol] = hprev[r];
    __syncthreads();
    // hidden vectors: [row][133] fp16 pairs
    for (int j = tid; j < ROWS * 133; j += NT) {
        int row = j / 133, i = j % 133;
        u32 v;
        if (i < 128) v = pack2(sHf[row * NH + 2 * i], sHf[row * NH + 2 * i + 1]);
        else if (i < 132) { int a = i - 128; v = pack2(sMisc[row][2 * a], sMisc[row][2 * a + 1]); }
        else v = pack2(sMisc[row][8], 0.f);
        sHid[row * 136 + i] = v;
    }
    __syncthreads();
    // L1: thread = (c,o) x 8 rows; sHid reads are wave-uniform (broadcast)
    {
        int co = tid & 511, rh = tid >> 9;
        int c = co >> 8, o = co & 255;
        float acc[8];
        float bv = b1[c * 256 + o];
        #pragma unroll
        for (int r = 0; r < 8; ++r) acc[r] = bv;
        const u32* wp = ws + OFF_W1 + c * 133 * 256 + o;
        const u32* hidp = sHid + rh * 8 * 136;
        for (int kk = 0; kk < 133; ++kk) {
            u32 wv = wp[kk * 256];
            #pragma unroll
            for (int r = 0; r < 8; ++r)
                acc[r] = fdot2(wv, hidp[r * 136 + kk], acc[r]);
        }
        #pragma unroll
        for (int r = 0; r < 8; ++r) {
            _Float16 a16 = (_Float16)fmaxf(acc[r], 0.f);
            ((u16*)sL1)[((rh * 8 + r) * 2 + c) * 256 + o] = __builtin_bit_cast(u16, a16);
        }
    }
    __syncthreads();
    // L2
    {
        int co = tid & 511, rh = tid >> 9;
        int c = co >> 8, o = co & 255;
        float acc[8];
        float bv = b2[c * 256 + o];
        #pragma unroll
        for (int r = 0; r < 8; ++r) acc[r] = bv;
        const u32* wp = ws + OFF_W2 + c * 128 * 256 + o;
        for (int kk = 0; kk < 128; ++kk) {
            u32 wv = wp[kk * 256];
            #pragma unroll
            for (int r = 0; r < 8; ++r)
                acc[r] = fdot2(wv, sL1[((rh * 8 + r) * 2 + c) * 128 + kk], acc[r]);
        }
        #pragma unroll
        for (int r = 0; r < 8; ++r) {
            _Float16 a16 = (_Float16)fmaxf(acc[r], 0.f);
            ((u16*)sL2)[((rh * 8 + r) * 2 + c) * 256 + o] = __builtin_bit_cast(u16, a16);
        }
    }
    __syncthreads();
    // L3: 32 outputs (16 rows x 2 critics), 16 lanes each + shfl reduce
    if (tid < 512) {
        int oid = tid >> 4;          // row*2 + c
        int kx  = tid & 15;
        int row = oid >> 1, c = oid & 1;
        const u32* wp = ws + OFF_W3 + c * 128 + kx * 8;
        const u32* hp = sL2 + (row * 2 + c) * 128 + kx * 8;
        float acc = 0.f;
        #pragma unroll
        for (int t2 = 0; t2 < 8; ++t2) acc = fdot2(wp[t2], hp[t2], acc);
        acc += __shfl_down(acc, 8);
        acc += __shfl_down(acc, 4);
        acc += __shfl_down(acc, 2);
        acc += __shfl_down(acc, 1);
        if (kx == 0) out[(bg * ROWS + row) * 2 + c] = acc + b3[c];
    }
}

extern "C" void kernel_launch(void* const* d_in, const int* in_sizes, int n_in,
                              void* d_out, int out_size, void* d_ws, size_t ws_size,
                              hipStream_t stream) {
    const float* particles = (const float*)d_in[0];
    const float* pweights  = (const float*)d_in[1];
    const float* actions   = (const float*)d_in[2];
    const float* timev     = (const float*)d_in[3];
    const float* Wi        = (const float*)d_in[4];
    const float* bi        = (const float*)d_in[5];
    const float* Whrz      = (const float*)d_in[6];
    const float* Whn       = (const float*)d_in[7];
    const float* bn        = (const float*)d_in[8];
    const float* W1        = (const float*)d_in[9];
    const float* b1        = (const float*)d_in[10];
    const float* W2        = (const float*)d_in[11];
    const float* b2        = (const float*)d_in[12];
    const float* W3        = (const float*)d_in[13];
    const float* b3        = (const float*)d_in[14];
    const int*   nts       = (const int*)d_in[15];
    u32* ws = (u32*)d_ws;
    float* outp = (float*)d_out;

    pack_kernel<<<(WS_DWORDS + 255) / 256, 256, 0, stream>>>(Wi, Whrz, Whn, W1, W2, W3, ws);
    qnet_kernel<<<NBLK, NT, 0, stream>>>(particles, pweights, actions, timev,
                                         bi, bn, b1, b2, b3, nts, ws, outp);
}

// Round 10
// 757.269 us; speedup vs baseline: 4.1281x; 4.1281x over previous
//
#include <hip/hip_runtime.h>
#include <hip/hip_fp16.h>

typedef _Float16 h2v __attribute__((ext_vector_type(2)));
typedef _Float16 f16x8 __attribute__((ext_vector_type(8)));
typedef float f32x4 __attribute__((ext_vector_type(4)));
typedef unsigned int u32;
typedef unsigned short u16;

#define NB 256
#define NP 512
#define NH 256

// ws layout in dwords
// WH: Wh B-frags. dword F = (((w*48 + f)*64 + l)*4 + d)
//   f = t*8 + kt; t = g*2 + c (g=gate 0..2, c=col-half 0..1), kt = K-tile 0..7
//   k = kt*32 + (l>>4)*8 + 2d (+1 for hi half), col = g*256 + w*32 + c*16 + (l&15)
#define OFF_WH 0
#define LEN_WH 98304            // 8 waves * 48 frags * 64 lanes * 4 dwords
// WIB: Wi B-frags (K=32, single K-tile, rows >=17 zero-padded)
//   dword F-OFF = ((w*6 + t)*64 + l)*4 + d ; k = (l>>4)*8 + 2d ; col as above
#define OFF_WIB (OFF_WH + LEN_WH)      // 98304
#define LEN_WIB 12288           // 8 * 6 * 64 * 4
#define OFF_W1 (OFF_WIB + LEN_WIB)     // 110592
#define LEN_W1 68096            // 2 * 133 * 256
#define OFF_W2 (OFF_W1 + LEN_W1)       // 178688
#define LEN_W2 65536            // 2 * 128 * 256
#define OFF_W3 (OFF_W2 + LEN_W2)       // 244224
#define LEN_W3 256              // 2 * 128
#define WS_DWORDS (OFF_W3 + LEN_W3)    // 244480 dwords

__device__ __forceinline__ u32 pack2(float lo, float hi) {
    h2v v; v.x = (_Float16)lo; v.y = (_Float16)hi;
    return __builtin_bit_cast(u32, v);
}

__device__ __forceinline__ float fdot2(u32 a, u32 b, float c) {
#if __has_builtin(__builtin_amdgcn_fdot2)
    return __builtin_amdgcn_fdot2(__builtin_bit_cast(h2v, a),
                                  __builtin_bit_cast(h2v, b), c, false);
#else
    h2v x = __builtin_bit_cast(h2v, a), y = __builtin_bit_cast(h2v, b);
    return c + (float)x.x * (float)y.x + (float)x.y * (float)y.y;
#endif
}

// ---------------- pack kernel ----------------
__global__ __launch_bounds__(256) void pack_kernel(
    const float* __restrict__ Wi, const float* __restrict__ Whrz,
    const float* __restrict__ Whn, const float* __restrict__ W1,
    const float* __restrict__ W2, const float* __restrict__ W3,
    u32* __restrict__ ws)
{
    for (int F = blockIdx.x * 256 + threadIdx.x; F < WS_DWORDS; F += gridDim.x * 256) {
        u32 val;
        if (F < OFF_WIB) {
            int d = F & 3; int r = F >> 2;
            int l = r & 63; int q = r >> 6;      // q = w*48 + f
            int f = q % 48; int w = q / 48;
            int t = f >> 3; int kt = f & 7;
            int g = t >> 1, c = t & 1;
            int k = kt * 32 + ((l >> 4) << 3) + 2 * d;
            int col = g * 256 + w * 32 + c * 16 + (l & 15);
            float lo, hi;
            if (col < 512) { lo = Whrz[k * 512 + col]; hi = Whrz[(k + 1) * 512 + col]; }
            else { lo = Whn[k * 256 + (col - 512)]; hi = Whn[(k + 1) * 256 + (col - 512)]; }
            val = pack2(lo, hi);
        } else if (F < OFF_W1) {
            int j = F - OFF_WIB;
            int d = j & 3; int r = j >> 2;
            int l = r & 63; int q2 = r >> 6;     // q2 = w*6 + t
            int t = q2 % 6; int w = q2 / 6;
            int g = t >> 1, c = t & 1;
            int k = ((l >> 4) << 3) + 2 * d;
            int col = g * 256 + w * 32 + c * 16 + (l & 15);
            float lo = (k < 17) ? Wi[k * 768 + col] : 0.f;
            float hi = (k + 1 < 17) ? Wi[(k + 1) * 768 + col] : 0.f;
            val = pack2(lo, hi);
        } else if (F < OFF_W2) {
            int j = F - OFF_W1; int c = j / (133 * 256); int r = j % (133 * 256);
            int kk = r >> 8; int o = r & 255;
            int k = 2 * kk;
            float lo = W1[(c * 265 + k) * 256 + o];
            float hi = (k + 1 < 265) ? W1[(c * 265 + k + 1) * 256 + o] : 0.f;
            val = pack2(lo, hi);
        } else if (F < OFF_W3) {
            int j = F - OFF_W2; int c = j >> 15; int r = j & 32767;
            int kk = r >> 8; int o = r & 255;
            float lo = W2[(c * 256 + 2 * kk) * 256 + o];
            float hi = W2[(c * 256 + 2 * kk + 1) * 256 + o];
            val = pack2(lo, hi);
        } else {
            int j = F - OFF_W3; int c = j >> 7; int jj = j & 127;
            float lo = W3[c * 256 + 2 * jj];
            float hi = W3[c * 256 + 2 * jj + 1];
            val = pack2(lo, hi);
        }
        ws[F] = val;
    }
}

// MFMA with B sourced directly from an AGPR ("a" input), accumulator in
// VGPR ("+v", normal init/readout — round 4's scratch storm came from
// asm-opaque "+a" accumulators). bfh's ONLY consumer is this "a" use, so
// regalloc keeps the 192-dword array in AGPRs copy-free.
#define MFMA_AB(acc, av, bf) \
    asm volatile("v_mfma_f32_16x16x32_f16 %0, %1, %2, %0" \
                 : "+v"(acc) : "v"(av), "a"(bf))

// ---------------- main kernel: one batch row per workgroup --------------
// Round-2 structure (610us champion) with one change: the 48 h@Wh MFMAs
// consume B-fragments resident in AGPRs via inline asm. Round 2's compiled
// form re-streamed the 384KB/step of B-frags from L2 every step (VGPR=128
// proves no residency); this removes that traffic + its address-calc VALU
// and vmcnt stalls. Wave w owns h-indices [w*32,w*32+32); gates in-register;
// one barrier/step; x@Wi precomputed on the MFMA pipe 16 steps at a time.
__global__ __launch_bounds__(512, 2) void qnet_kernel(
    const float* __restrict__ particles, const float* __restrict__ pweights,
    const float* __restrict__ actions, const float* __restrict__ timev,
    const float* __restrict__ bi, const float* __restrict__ bn,
    const float* __restrict__ b1, const float* __restrict__ b2,
    const float* __restrict__ b3, const int* __restrict__ nts,
    const u32* __restrict__ ws, float* __restrict__ out)
{
    __shared__ __align__(16) u32 sX[NP * 16];      // 32768 B
    __shared__ __align__(16) float sG[8 * 1536];   // 49152 B
    __shared__ __align__(16) u16 sH2[2][NH];       // 1024 B
    __shared__ __align__(16) float sHf[NH];        // 1024 B
    __shared__ __align__(16) float sMisc[16];      // 64 B

    const int b = blockIdx.x;
    const int tid = threadIdx.x;
    const int lane = tid & 63;
    const int wid = tid >> 6;   // 0..7

    // ---- Wh B-frags: load once; consumed ONLY by MFMA_AB "a" inputs ----
    f16x8 bfh[48];
    {
        const uint4* gp = (const uint4*)(ws + OFF_WH) + (wid * 48) * 64 + lane;
        #pragma unroll
        for (int i = 0; i < 48; ++i) bfh[i] = __builtin_bit_cast(f16x8, gp[i * 64]);
    }
    // ---- stage x rows as fp16 pairs, padded to 16 pairs (K=32 halves) ----
    {
        const float2* pr2 = (const float2*)(particles + (long)b * NP * 16);
        for (int j = tid; j < NP * 8; j += 512) {
            int p = j >> 3, q = j & 7;
            float2 v = pr2[j];
            sX[p * 16 + q] = pack2(v.x, v.y);
        }
        const float* wr = pweights + (long)b * NP;
        for (int j = tid; j < NP * 8; j += 512) {
            int p = j >> 3, q = j & 7;
            sX[p * 16 + 8 + q] = (q == 0) ? pack2(wr[p], 0.f) : 0u;
        }
    }
    if (tid < 256) ((u32*)sH2)[tid] = 0u;
    if (tid < 8) sMisc[tid] = actions[b * 8 + tid];
    if (tid == 8) sMisc[8] = timev[b] / (float)nts[0];

    float birL = 0.f, bizL = 0.f, binnL = 0.f, bnnL = 0.f, hreg = 0.f;
    if (lane < 32) {
        int j = wid * 32 + lane;
        birL = bi[j]; bizL = bi[NH + j]; binnL = bi[2 * NH + j]; bnnL = bn[j];
    }
    __syncthreads();

    const uint4* wibp = (const uint4*)(ws + OFF_WIB) + (wid * 6) * 64 + lane;

    #pragma unroll 1
    for (int p = 0; p < NP; ++p) {
        if ((p & 15) == 0) {
            // ---- x@Wi for steps p..p+15 (intrinsic MFMA, pairwise) ----
            f16x8 av = __builtin_bit_cast(f16x8,
                ((const uint4*)sX)[(p + (lane & 15)) * 4 + (lane >> 4)]);
            f32x4 z4 = {0.f, 0.f, 0.f, 0.f};
            int sb = (lane >> 4) << 2;
            float* gw = sG + wid * 1536 + (lane & 15);
            {
                f32x4 g0 = __builtin_amdgcn_mfma_f32_16x16x32_f16(av, __builtin_bit_cast(f16x8, wibp[0 * 64]), z4, 0, 0, 0);
                f32x4 g1 = __builtin_amdgcn_mfma_f32_16x16x32_f16(av, __builtin_bit_cast(f16x8, wibp[1 * 64]), z4, 0, 0, 0);
                #pragma unroll
                for (int r = 0; r < 4; ++r) {
                    gw[(sb + r) * 32]      = g0[r];
                    gw[(sb + r) * 32 + 16] = g1[r];
                }
            }
            {
                f32x4 g2 = __builtin_amdgcn_mfma_f32_16x16x32_f16(av, __builtin_bit_cast(f16x8, wibp[2 * 64]), z4, 0, 0, 0);
                f32x4 g3 = __builtin_amdgcn_mfma_f32_16x16x32_f16(av, __builtin_bit_cast(f16x8, wibp[3 * 64]), z4, 0, 0, 0);
                #pragma unroll
                for (int r = 0; r < 4; ++r) {
                    gw[512 + (sb + r) * 32]      = g2[r];
                    gw[512 + (sb + r) * 32 + 16] = g3[r];
                }
            }
            {
                f32x4 g4 = __builtin_amdgcn_mfma_f32_16x16x32_f16(av, __builtin_bit_cast(f16x8, wibp[4 * 64]), z4, 0, 0, 0);
                f32x4 g5 = __builtin_amdgcn_mfma_f32_16x16x32_f16(av, __builtin_bit_cast(f16x8, wibp[5 * 64]), z4, 0, 0, 0);
                #pragma unroll
                for (int r = 0; r < 4; ++r) {
                    gw[1024 + (sb + r) * 32]      = g4[r];
                    gw[1024 + (sb + r) * 32 + 16] = g5[r];
                }
            }
            __syncthreads();
        }

        // ---- this step's x@Wi sums (independent of h, read early) ----
        float gR, gZ, gN;
        {
            const float* gp = sG + wid * 1536 + (p & 15) * 32 + (lane & 31);
            gR = gp[0]; gZ = gp[512]; gN = gp[1024];
        }

        // ---- h@Wh: 6 gate-tiles x 8 chained K-tiles, B from AGPRs ----
        const u32* hbuf = (const u32*)(&sH2[p & 1][0]);
        f32x4 a0 = {0.f, 0.f, 0.f, 0.f}, a1 = a0, a2 = a0, a3 = a0, a4 = a0, a5 = a0;
        // VALU-write -> MFMA-srcC wait states (asm hides the MFMA from the
        // compiler's hazard recognizer)
        asm volatile("s_nop 1\n\ts_nop 1"
                     : "+v"(a0), "+v"(a1), "+v"(a2), "+v"(a3), "+v"(a4), "+v"(a5));
        #pragma unroll
        for (int kt = 0; kt < 8; ++kt) {
            f16x8 hv = __builtin_bit_cast(f16x8, ((const uint4*)hbuf)[kt * 4 + (lane >> 4)]);
            MFMA_AB(a0, hv, bfh[kt]);
            MFMA_AB(a1, hv, bfh[8 + kt]);
            MFMA_AB(a2, hv, bfh[16 + kt]);
            MFMA_AB(a3, hv, bfh[24 + kt]);
            MFMA_AB(a4, hv, bfh[32 + kt]);
            MFMA_AB(a5, hv, bfh[40 + kt]);
        }
        // MFMA-write -> VALU-read wait states
        asm volatile("s_nop 7\n\ts_nop 7\n\ts_nop 7"
                     : "+v"(a0), "+v"(a1), "+v"(a2), "+v"(a3), "+v"(a4), "+v"(a5));

        // ---- gates fully in-register (lane l<32 owns h[wid*32+l]) ----
        bool hic = (lane & 16) != 0;
        float srm = hic ? a1[0] : a0[0];
        float szm = hic ? a3[0] : a2[0];
        float snm = hic ? a5[0] : a4[0];
        if (lane < 32) {
            float xr = gR + birL + srm;
            float xz = gZ + bizL + szm;
            float xn = gN + binnL;
            float r = 1.f / (1.f + __expf(-xr));
            float z = 1.f / (1.f + __expf(-xz));
            float targ = xn + r * (snm + bnnL);
            float e2 = __expf(2.f * targ);
            float n = 1.f - 2.f / (e2 + 1.f);
            hreg = (1.f - z) * n + z * hreg;
            _Float16 hh = (_Float16)hreg;
            sH2[(p + 1) & 1][wid * 32 + lane] = __builtin_bit_cast(u16, hh);
        }
        __syncthreads();
    }

    // ---------------- MLP tail ----------------
    if (lane < 32) sHf[wid * 32 + lane] = hreg;
    __syncthreads();
    u32* sHid = (u32*)sG;             // 133 dwords
    u16* sL1 = (u16*)(sG + 512);      // 512 halves
    u16* sL2 = (u16*)(sG + 1024);     // 512 halves
    if (tid < 128) sHid[tid] = pack2(sHf[2 * tid], sHf[2 * tid + 1]);
    else if (tid < 132) { int i = tid - 128; sHid[tid] = pack2(sMisc[2 * i], sMisc[2 * i + 1]); }
    else if (tid == 132) sHid[132] = pack2(sMisc[8], 0.f);
    __syncthreads();
    // L1: 512 outputs (2 critics x 256)
    {
        int c = tid >> 8, o = tid & 255;
        float acc = b1[c * 256 + o];
        const u32* wp = ws + OFF_W1 + c * 133 * 256 + o;
        #pragma unroll 4
        for (int kk = 0; kk < 133; ++kk) acc = fdot2(wp[kk * 256], sHid[kk], acc);
        acc = fmaxf(acc, 0.f);
        _Float16 a16 = (_Float16)acc;
        sL1[tid] = __builtin_bit_cast(u16, a16);
    }
    __syncthreads();
    // L2
    {
        int c = tid >> 8, o = tid & 255;
        float acc = b2[c * 256 + o];
        const u32* wp = ws + OFF_W2 + c * 128 * 256 + o;
        const u32* hp = (const u32*)sL1 + c * 128;
        #pragma unroll 4
        for (int kk = 0; kk < 128; ++kk) acc = fdot2(wp[kk * 256], hp[kk], acc);
        acc = fmaxf(acc, 0.f);
        _Float16 a16 = (_Float16)acc;
        sL2[tid] = __builtin_bit_cast(u16, a16);
    }
    __syncthreads();
    // L3: 2 outputs via wave reduction
    if (tid < 128) {
        int c = tid >> 6, l = tid & 63;
        const u32* wp = ws + OFF_W3 + c * 128;
        const u32* hp = (const u32*)sL2 + c * 128;
        float acc = fdot2(wp[l], hp[l], 0.f);
        acc = fdot2(wp[64 + l], hp[64 + l], acc);
        #pragma unroll
        for (int off = 32; off > 0; off >>= 1) acc += __shfl_down(acc, off);
        if (l == 0) out[b * 2 + c] = acc + b3[c];
    }
}

extern "C" void kernel_launch(void* const* d_in, const int* in_sizes, int n_in,
                              void* d_out, int out_size, void* d_ws, size_t ws_size,
                              hipStream_t stream) {
    const float* particles = (const float*)d_in[0];
    const float* pweights  = (const float*)d_in[1];
    const float* actions   = (const float*)d_in[2];
    const float* timev     = (const float*)d_in[3];
    const float* Wi        = (const float*)d_in[4];
    const float* bi        = (const float*)d_in[5];
    const float* Whrz      = (const float*)d_in[6];
    const float* Whn       = (const float*)d_in[7];
    const float* bn        = (const float*)d_in[8];
    const float* W1        = (const float*)d_in[9];
    const float* b1        = (const float*)d_in[10];
    const float* W2        = (const float*)d_in[11];
    const float* b2        = (const float*)d_in[12];
    const float* W3        = (const float*)d_in[13];
    const float* b3        = (const float*)d_in[14];
    const int*   nts       = (const int*)d_in[15];
    u32* ws = (u32*)d_ws;
    float* outp = (float*)d_out;

    pack_kernel<<<(WS_DWORDS + 255) / 256, 256, 0, stream>>>(Wi, Whrz, Whn, W1, W2, W3, ws);
    qnet_kernel<<<NB, 512, 0, stream>>>(particles, pweights, actions, timev,
                                        bi, bn, b1, b2, b3, nts, ws, outp);
}